// Round 1
// baseline (786.530 us; speedup 1.0000x reference)
//
#include <hip/hip_runtime.h>

// Inputs (setup_inputs order):
// 0: features [N,64] f32
// 1: receivers [E] i32
// 2: relative_positions [E,2] f32
// 3: window_support [1] f32
// 4: a (senders) [E] i32
// 5: kernel [4,2,64,64] f32
// 6: bias [64] f32
// out: [N,64] f32

#define KH 4
#define KW 4
#define T_TAPS 16

// ---------------- Phase 1: edge scatter into A[N,16,chunk] ----------------
__global__ __launch_bounds__(256) void ascc_scatter(
    float* __restrict__ A,
    const float* __restrict__ features,
    const int* __restrict__ receivers,
    const float* __restrict__ relpos,
    const float* __restrict__ wsup,
    const int* __restrict__ senders,
    int c0, int chunk, int E)
{
    int lane = threadIdx.x & 63;
    int e = (blockIdx.x << 2) + (threadIdx.x >> 6);
    if (e >= E) return;

    float ws = wsup[0];
    float u0 = relpos[2 * e] / ws;
    float u1 = relpos[2 * e + 1] / ws;
    u0 = fminf(fmaxf(u0, -1.f), 1.f);
    u1 = fminf(fmaxf(u1, -1.f), 1.f);
    float gx = (u0 + 1.f) * 1.5f;   // (u+1)*0.5*(KH-1)
    float gy = (u1 + 1.f) * 1.5f;   // (u+1)*0.5*(KW-1)
    float x0f = fminf(fmaxf(floorf(gx), 0.f), 2.f);
    float y0f = fminf(fmaxf(floorf(gy), 0.f), 2.f);
    float fx = gx - x0f;
    float fy = gy - y0f;
    float w00 = (1.f - fx) * (1.f - fy);
    float w01 = (1.f - fx) * fy;
    float w10 = fx * (1.f - fy);
    float w11 = fx * fy;
    float r2 = u0 * u0 + u1 * u1;
    float win = fmaxf(1.f - r2, 0.f);
    win = win * win * win;

    int x0i = (int)x0f, y0i = (int)y0f;
    int r = receivers[e];
    int s = senders[e];

    if (lane < chunk) {
        float g = features[(size_t)s * 64 + c0 + lane] * win;
        float* base = A + ((size_t)r * T_TAPS + x0i * 4 + y0i) * chunk + lane;
        atomicAdd(base,             w00 * g);
        atomicAdd(base + chunk,     w01 * g);   // (x0, y0+1)
        atomicAdd(base + 4 * chunk, w10 * g);   // (x0+1, y0)
        atomicAdd(base + 5 * chunk, w11 * g);   // (x0+1, y0+1)
    }
}

// ---------------- Phase 2: out[n,o] (+)= sum_k A[n,k] * Kfull[k,o] ----------
// Kfull[t,i,o]: t=x*4+y; y<2 -> kernel[x][y][i][o]; y>=2 -> -kernel[3-x][3-y][i][o]
template <int CHUNK>
__global__ __launch_bounds__(256) void ascc_gemm(
    float* __restrict__ out,
    const float* __restrict__ A,
    const float* __restrict__ kern,
    const float* __restrict__ bias,
    int c0, int first, int Nn)
{
    __shared__ float A_lds[64][68];
    __shared__ float K_lds[64][68];

    const int tid = threadIdx.x;
    const int n0 = blockIdx.x * 64;
    const int tn = tid >> 4;   // 0..15 -> node quad
    const int to = tid & 15;   // 0..15 -> out quad
    const int Ktot = T_TAPS * CHUNK;

    float acc[4][4] = {{0.f, 0.f, 0.f, 0.f}, {0.f, 0.f, 0.f, 0.f},
                       {0.f, 0.f, 0.f, 0.f}, {0.f, 0.f, 0.f, 0.f}};

    for (int kc = 0; kc < Ktot; kc += 64) {
        __syncthreads();
        // ---- stage A tile: 64 nodes x 64 k
        #pragma unroll
        for (int it = 0; it < 4; ++it) {
            int row = (tid >> 4) + (it << 4);
            int col = (tid & 15) << 2;
            float4 v = make_float4(0.f, 0.f, 0.f, 0.f);
            int n = n0 + row;
            if (n < Nn) v = *(const float4*)(A + (size_t)n * Ktot + kc + col);
            *(float4*)&A_lds[row][col] = v;
        }
        // ---- stage K tile: 64 k-rows x 64 outs (antisymmetrize on the fly)
        #pragma unroll
        for (int it = 0; it < 4; ++it) {
            int krow = (tid >> 4) + (it << 4);
            int o4 = (tid & 15) << 2;
            int kglob = kc + krow;
            int t = kglob / CHUNK;
            int ci = kglob % CHUNK;
            int i = c0 + ci;
            int x = t >> 2, y = t & 3;
            const float* src;
            float sign;
            if (y < 2) { src = kern + (((size_t)x * 2 + y) * 64 + i) * 64;             sign =  1.f; }
            else       { src = kern + (((size_t)(3 - x) * 2 + (3 - y)) * 64 + i) * 64; sign = -1.f; }
            float4 v = *(const float4*)(src + o4);
            v.x *= sign; v.y *= sign; v.z *= sign; v.w *= sign;
            *(float4*)&K_lds[krow][o4] = v;
        }
        __syncthreads();
        // ---- compute: 4n x 4o per thread
        for (int k = 0; k < 64; k += 4) {
            float4 a[4], b[4];
            #pragma unroll
            for (int j = 0; j < 4; ++j) a[j] = *(const float4*)&A_lds[(tn << 2) + j][k];
            #pragma unroll
            for (int j = 0; j < 4; ++j) b[j] = *(const float4*)&K_lds[k + j][to << 2];
            #pragma unroll
            for (int nj = 0; nj < 4; ++nj) {
                const float av[4] = {a[nj].x, a[nj].y, a[nj].z, a[nj].w};
                #pragma unroll
                for (int kk = 0; kk < 4; ++kk) {
                    acc[nj][0] += av[kk] * b[kk].x;
                    acc[nj][1] += av[kk] * b[kk].y;
                    acc[nj][2] += av[kk] * b[kk].z;
                    acc[nj][3] += av[kk] * b[kk].w;
                }
            }
        }
    }

    // ---- epilogue
    #pragma unroll
    for (int nj = 0; nj < 4; ++nj) {
        int n = n0 + (tn << 2) + nj;
        if (n >= Nn) continue;
        size_t off = (size_t)n * 64 + (to << 2);
        if (first) {
            float4 bv = *(const float4*)(bias + (to << 2));
            float4 rv;
            rv.x = acc[nj][0] + bv.x;
            rv.y = acc[nj][1] + bv.y;
            rv.z = acc[nj][2] + bv.z;
            rv.w = acc[nj][3] + bv.w;
            *(float4*)(out + off) = rv;
        } else {
            float4 cur = *(const float4*)(out + off);
            cur.x += acc[nj][0];
            cur.y += acc[nj][1];
            cur.z += acc[nj][2];
            cur.w += acc[nj][3];
            *(float4*)(out + off) = cur;
        }
    }
}

extern "C" void kernel_launch(void* const* d_in, const int* in_sizes, int n_in,
                              void* d_out, int out_size, void* d_ws, size_t ws_size,
                              hipStream_t stream) {
    const float* features  = (const float*)d_in[0];
    const int*   receivers = (const int*)d_in[1];
    const float* relpos    = (const float*)d_in[2];
    const float* wsup      = (const float*)d_in[3];
    const int*   senders   = (const int*)d_in[4];
    const float* kern      = (const float*)d_in[5];
    const float* bias      = (const float*)d_in[6];
    float* out = (float*)d_out;
    float* A   = (float*)d_ws;

    const int Nn = in_sizes[0] / 64;
    const int E  = in_sizes[1];

    // pick largest channel chunk whose A buffer fits in workspace
    int chunk = 64;
    while ((size_t)Nn * T_TAPS * chunk * sizeof(float) > ws_size && chunk > 4) chunk >>= 1;

    int first = 1;
    for (int c0 = 0; c0 < 64; c0 += chunk) {
        hipMemsetAsync(A, 0, (size_t)Nn * T_TAPS * chunk * sizeof(float), stream);
        ascc_scatter<<<dim3((E + 3) / 4), dim3(256), 0, stream>>>(
            A, features, receivers, relpos, wsup, senders, c0, chunk, E);
        dim3 ggrid((Nn + 63) / 64);
        switch (chunk) {
            case 64: ascc_gemm<64><<<ggrid, dim3(256), 0, stream>>>(out, A, kern, bias, c0, first, Nn); break;
            case 32: ascc_gemm<32><<<ggrid, dim3(256), 0, stream>>>(out, A, kern, bias, c0, first, Nn); break;
            case 16: ascc_gemm<16><<<ggrid, dim3(256), 0, stream>>>(out, A, kern, bias, c0, first, Nn); break;
            case  8: ascc_gemm< 8><<<ggrid, dim3(256), 0, stream>>>(out, A, kern, bias, c0, first, Nn); break;
            default: ascc_gemm< 4><<<ggrid, dim3(256), 0, stream>>>(out, A, kern, bias, c0, first, Nn); break;
        }
        first = 0;
    }
}

// Round 2
// 451.784 us; speedup vs baseline: 1.7409x; 1.7409x over previous
//
#include <hip/hip_runtime.h>

// Inputs (setup_inputs order):
// 0: features [N,64] f32
// 1: receivers [E] i32
// 2: relative_positions [E,2] f32
// 3: window_support [1] f32
// 4: a (senders) [E] i32
// 5: kernel [4,2,64,64] f32
// 6: bias [64] f32
// out: [N,64] f32

#define T_TAPS 16

// ---------------- CSR build ----------------
__global__ __launch_bounds__(256) void ascc_hist(
    int* __restrict__ cnt, const int* __restrict__ receivers, int E)
{
    int e = blockIdx.x * 256 + threadIdx.x;
    if (e < E) atomicAdd(&cnt[receivers[e]], 1);
}

// single-block exclusive scan, 4 elements/thread per chunk of 4096
__global__ __launch_bounds__(1024) void ascc_scan(
    int* __restrict__ off, const int* __restrict__ cnt, int Nn)
{
    __shared__ int s[1024];
    int running = 0;
    for (int base = 0; base < Nn; base += 4096) {
        int i0 = base + threadIdx.x * 4;
        int x0 = (i0 + 0 < Nn) ? cnt[i0 + 0] : 0;
        int x1 = (i0 + 1 < Nn) ? cnt[i0 + 1] : 0;
        int x2 = (i0 + 2 < Nn) ? cnt[i0 + 2] : 0;
        int x3 = (i0 + 3 < Nn) ? cnt[i0 + 3] : 0;
        int tsum = x0 + x1 + x2 + x3;
        s[threadIdx.x] = tsum;
        __syncthreads();
        #pragma unroll
        for (int d = 1; d < 1024; d <<= 1) {
            int t = (threadIdx.x >= (unsigned)d) ? s[threadIdx.x - d] : 0;
            __syncthreads();
            s[threadIdx.x] += t;
            __syncthreads();
        }
        int excl = running + s[threadIdx.x] - tsum;
        if (i0 + 0 < Nn) off[i0 + 0] = excl;
        if (i0 + 1 < Nn) off[i0 + 1] = excl + x0;
        if (i0 + 2 < Nn) off[i0 + 2] = excl + x0 + x1;
        if (i0 + 3 < Nn) off[i0 + 3] = excl + x0 + x1 + x2;
        running += s[1023];
        __syncthreads();
    }
    if (threadIdx.x == 0) off[Nn] = running;
}

__global__ __launch_bounds__(256) void ascc_copy(
    int* __restrict__ cur, const int* __restrict__ off, int Nn)
{
    int i = blockIdx.x * 256 + threadIdx.x;
    if (i < Nn) cur[i] = off[i];
}

__global__ __launch_bounds__(256) void ascc_fill(
    int* __restrict__ eid, int* __restrict__ cur,
    const int* __restrict__ receivers, int E)
{
    int e = blockIdx.x * 256 + threadIdx.x;
    if (e < E) {
        int p = atomicAdd(&cur[receivers[e]], 1);
        eid[p] = e;
    }
}

// ---------------- Phase 1: per-receiver register accumulation --------------
// one wave per receiver; lane = channel; acc[16] taps in VGPRs; no atomics
__global__ __launch_bounds__(256) void ascc_accum(
    float* __restrict__ A,
    const float* __restrict__ features,
    const int* __restrict__ off,
    const int* __restrict__ eid,
    const float* __restrict__ relpos,
    const float* __restrict__ wsup,
    const int* __restrict__ senders,
    int c0, int chunk, int Nn)
{
    int lane = threadIdx.x & 63;
    int r = blockIdx.x * 4 + (threadIdx.x >> 6);
    if (r >= Nn) return;

    float ws = wsup[0];
    float acc[T_TAPS];
    #pragma unroll
    for (int t = 0; t < T_TAPS; ++t) acc[t] = 0.f;

    int j0 = off[r], j1 = off[r + 1];
    for (int j = j0; j < j1; ++j) {
        int e = eid[j];
        float u0 = relpos[2 * e] / ws;
        float u1 = relpos[2 * e + 1] / ws;
        u0 = fminf(fmaxf(u0, -1.f), 1.f);
        u1 = fminf(fmaxf(u1, -1.f), 1.f);
        float gx = (u0 + 1.f) * 1.5f;
        float gy = (u1 + 1.f) * 1.5f;
        float x0f = fminf(fmaxf(floorf(gx), 0.f), 2.f);
        float y0f = fminf(fmaxf(floorf(gy), 0.f), 2.f);
        float fx = gx - x0f;
        float fy = gy - y0f;
        int x0i = (int)x0f, y0i = (int)y0f;
        float r2 = u0 * u0 + u1 * u1;
        float win = fmaxf(1.f - r2, 0.f);
        win = win * win * win;

        float wx[4], wy[4];
        #pragma unroll
        for (int k = 0; k < 4; ++k)
            wx[k] = (k == x0i) ? (1.f - fx) : ((k == x0i + 1) ? fx : 0.f);
        #pragma unroll
        for (int k = 0; k < 4; ++k)
            wy[k] = (k == y0i) ? (1.f - fy) : ((k == y0i + 1) ? fy : 0.f);

        int s = senders[e];
        float g = (lane < chunk) ? features[(size_t)s * 64 + c0 + lane] * win : 0.f;
        float wyg[4];
        #pragma unroll
        for (int k = 0; k < 4; ++k) wyg[k] = wy[k] * g;
        #pragma unroll
        for (int t = 0; t < T_TAPS; ++t)
            acc[t] += wx[t >> 2] * wyg[t & 3];
    }

    if (lane < chunk) {
        float* base = A + (size_t)r * T_TAPS * chunk + lane;
        #pragma unroll
        for (int t = 0; t < T_TAPS; ++t) base[(size_t)t * chunk] = acc[t];
    }
}

// ---------------- Phase 2: out[n,o] (+)= sum_k A[n,k] * Kfull[k,o] ----------
template <int CHUNK>
__global__ __launch_bounds__(256) void ascc_gemm(
    float* __restrict__ out,
    const float* __restrict__ A,
    const float* __restrict__ kern,
    const float* __restrict__ bias,
    int c0, int first, int Nn)
{
    __shared__ float A_lds[64][68];
    __shared__ float K_lds[64][68];

    const int tid = threadIdx.x;
    const int n0 = blockIdx.x * 64;
    const int tn = tid >> 4;
    const int to = tid & 15;
    const int Ktot = T_TAPS * CHUNK;

    float acc[4][4] = {{0.f, 0.f, 0.f, 0.f}, {0.f, 0.f, 0.f, 0.f},
                       {0.f, 0.f, 0.f, 0.f}, {0.f, 0.f, 0.f, 0.f}};

    for (int kc = 0; kc < Ktot; kc += 64) {
        __syncthreads();
        #pragma unroll
        for (int it = 0; it < 4; ++it) {
            int row = (tid >> 4) + (it << 4);
            int col = (tid & 15) << 2;
            float4 v = make_float4(0.f, 0.f, 0.f, 0.f);
            int n = n0 + row;
            if (n < Nn) v = *(const float4*)(A + (size_t)n * Ktot + kc + col);
            *(float4*)&A_lds[row][col] = v;
        }
        #pragma unroll
        for (int it = 0; it < 4; ++it) {
            int krow = (tid >> 4) + (it << 4);
            int o4 = (tid & 15) << 2;
            int kglob = kc + krow;
            int t = kglob / CHUNK;
            int ci = kglob % CHUNK;
            int i = c0 + ci;
            int x = t >> 2, y = t & 3;
            const float* src;
            float sign;
            if (y < 2) { src = kern + (((size_t)x * 2 + y) * 64 + i) * 64;             sign =  1.f; }
            else       { src = kern + (((size_t)(3 - x) * 2 + (3 - y)) * 64 + i) * 64; sign = -1.f; }
            float4 v = *(const float4*)(src + o4);
            v.x *= sign; v.y *= sign; v.z *= sign; v.w *= sign;
            *(float4*)&K_lds[krow][o4] = v;
        }
        __syncthreads();
        for (int k = 0; k < 64; k += 4) {
            float4 a[4], b[4];
            #pragma unroll
            for (int j = 0; j < 4; ++j) a[j] = *(const float4*)&A_lds[(tn << 2) + j][k];
            #pragma unroll
            for (int j = 0; j < 4; ++j) b[j] = *(const float4*)&K_lds[k + j][to << 2];
            #pragma unroll
            for (int nj = 0; nj < 4; ++nj) {
                const float av[4] = {a[nj].x, a[nj].y, a[nj].z, a[nj].w};
                #pragma unroll
                for (int kk = 0; kk < 4; ++kk) {
                    acc[nj][0] += av[kk] * b[kk].x;
                    acc[nj][1] += av[kk] * b[kk].y;
                    acc[nj][2] += av[kk] * b[kk].z;
                    acc[nj][3] += av[kk] * b[kk].w;
                }
            }
        }
    }

    #pragma unroll
    for (int nj = 0; nj < 4; ++nj) {
        int n = n0 + (tn << 2) + nj;
        if (n >= Nn) continue;
        size_t offo = (size_t)n * 64 + (to << 2);
        if (first) {
            float4 bv = *(const float4*)(bias + (to << 2));
            float4 rv;
            rv.x = acc[nj][0] + bv.x;
            rv.y = acc[nj][1] + bv.y;
            rv.z = acc[nj][2] + bv.z;
            rv.w = acc[nj][3] + bv.w;
            *(float4*)(out + offo) = rv;
        } else {
            float4 cur = *(const float4*)(out + offo);
            cur.x += acc[nj][0];
            cur.y += acc[nj][1];
            cur.z += acc[nj][2];
            cur.w += acc[nj][3];
            *(float4*)(out + offo) = cur;
        }
    }
}

extern "C" void kernel_launch(void* const* d_in, const int* in_sizes, int n_in,
                              void* d_out, int out_size, void* d_ws, size_t ws_size,
                              hipStream_t stream) {
    const float* features  = (const float*)d_in[0];
    const int*   receivers = (const int*)d_in[1];
    const float* relpos    = (const float*)d_in[2];
    const float* wsup      = (const float*)d_in[3];
    const int*   senders   = (const int*)d_in[4];
    const float* kern      = (const float*)d_in[5];
    const float* bias      = (const float*)d_in[6];
    float* out = (float*)d_out;

    const int Nn = in_sizes[0] / 64;
    const int E  = in_sizes[1];

    // workspace layout: off[N+1] | cur[N] | eid[E] | A[N*16*chunk]
    char* w = (char*)d_ws;
    size_t p = 0;
    int* off = (int*)(w + p); p += ((size_t)(Nn + 1) * 4 + 255) & ~(size_t)255;
    int* cur = (int*)(w + p); p += ((size_t)Nn * 4 + 255) & ~(size_t)255;
    int* eid = (int*)(w + p); p += ((size_t)E * 4 + 255) & ~(size_t)255;
    float* A = (float*)(w + p);
    size_t a_bytes = ws_size - p;

    int chunk = 64;
    while ((size_t)Nn * T_TAPS * chunk * sizeof(float) > a_bytes && chunk > 4) chunk >>= 1;

    dim3 ge((E + 255) / 256), gn((Nn + 255) / 256);

    // CSR build (cur doubles as the histogram buffer)
    hipMemsetAsync(cur, 0, (size_t)Nn * sizeof(int), stream);
    ascc_hist<<<ge, dim3(256), 0, stream>>>(cur, receivers, E);
    ascc_scan<<<dim3(1), dim3(1024), 0, stream>>>(off, cur, Nn);
    ascc_copy<<<gn, dim3(256), 0, stream>>>(cur, off, Nn);
    ascc_fill<<<ge, dim3(256), 0, stream>>>(eid, cur, receivers, E);

    int first = 1;
    for (int c0 = 0; c0 < 64; c0 += chunk) {
        ascc_accum<<<dim3((Nn + 3) / 4), dim3(256), 0, stream>>>(
            A, features, off, eid, relpos, wsup, senders, c0, chunk, Nn);
        dim3 ggrid((Nn + 63) / 64);
        switch (chunk) {
            case 64: ascc_gemm<64><<<ggrid, dim3(256), 0, stream>>>(out, A, kern, bias, c0, first, Nn); break;
            case 32: ascc_gemm<32><<<ggrid, dim3(256), 0, stream>>>(out, A, kern, bias, c0, first, Nn); break;
            case 16: ascc_gemm<16><<<ggrid, dim3(256), 0, stream>>>(out, A, kern, bias, c0, first, Nn); break;
            case  8: ascc_gemm< 8><<<ggrid, dim3(256), 0, stream>>>(out, A, kern, bias, c0, first, Nn); break;
            default: ascc_gemm< 4><<<ggrid, dim3(256), 0, stream>>>(out, A, kern, bias, c0, first, Nn); break;
        }
        first = 0;
    }
}

// Round 3
// 287.810 us; speedup vs baseline: 2.7328x; 1.5697x over previous
//
#include <hip/hip_runtime.h>
#include <hip/hip_bf16.h>

// Inputs: 0 features[N,64] f32 | 1 receivers[E] i32 | 2 relpos[E,2] f32
//         3 window_support[1] f32 | 4 senders[E] i32 | 5 kernel[4,2,64,64] f32
//         6 bias[64] f32   -> out [N,64] f32

#define T_TAPS 16

typedef unsigned short u16;
typedef short s16x8 __attribute__((ext_vector_type(8)));
typedef u16 u16x8 __attribute__((ext_vector_type(8)));
typedef float f32x4 __attribute__((ext_vector_type(4)));

static __device__ __forceinline__ u16 f2bf(float x) {
    union { float f; unsigned u; } v; v.f = x;
    unsigned r = v.u + 0x7FFF + ((v.u >> 16) & 1);
    return (u16)(r >> 16);
}

// ---------------- CSR build ----------------
__global__ __launch_bounds__(256) void ascc_hist(
    int* __restrict__ cnt, const int* __restrict__ receivers, int E)
{
    int e = blockIdx.x * 256 + threadIdx.x;
    if (e < E) atomicAdd(&cnt[receivers[e]], 1);
}

__global__ __launch_bounds__(1024) void ascc_scan(
    int* __restrict__ off, const int* __restrict__ cnt, int Nn)
{
    __shared__ int s[1024];
    int running = 0;
    for (int base = 0; base < Nn; base += 4096) {
        int i0 = base + threadIdx.x * 4;
        int x0 = (i0 + 0 < Nn) ? cnt[i0 + 0] : 0;
        int x1 = (i0 + 1 < Nn) ? cnt[i0 + 1] : 0;
        int x2 = (i0 + 2 < Nn) ? cnt[i0 + 2] : 0;
        int x3 = (i0 + 3 < Nn) ? cnt[i0 + 3] : 0;
        int tsum = x0 + x1 + x2 + x3;
        s[threadIdx.x] = tsum;
        __syncthreads();
        #pragma unroll
        for (int d = 1; d < 1024; d <<= 1) {
            int t = (threadIdx.x >= (unsigned)d) ? s[threadIdx.x - d] : 0;
            __syncthreads();
            s[threadIdx.x] += t;
            __syncthreads();
        }
        int excl = running + s[threadIdx.x] - tsum;
        if (i0 + 0 < Nn) off[i0 + 0] = excl;
        if (i0 + 1 < Nn) off[i0 + 1] = excl + x0;
        if (i0 + 2 < Nn) off[i0 + 2] = excl + x0 + x1;
        if (i0 + 3 < Nn) off[i0 + 3] = excl + x0 + x1 + x2;
        running += s[1023];
        __syncthreads();
    }
    if (threadIdx.x == 0) off[Nn] = running;
}

__global__ __launch_bounds__(256) void ascc_copy(
    int* __restrict__ cur, const int* __restrict__ off, int Nn)
{
    int i = blockIdx.x * 256 + threadIdx.x;
    if (i < Nn) cur[i] = off[i];
}

__global__ __launch_bounds__(256) void ascc_fill(
    int* __restrict__ eid, int* __restrict__ cur,
    const int* __restrict__ receivers, int E)
{
    int e = blockIdx.x * 256 + threadIdx.x;
    if (e < E) {
        int p = atomicAdd(&cur[receivers[e]], 1);
        eid[p] = e;
    }
}

// ---------------- edge-record precompute (sorted order, coalesced writes) ---
__global__ __launch_bounds__(256) void ascc_prep(
    int* __restrict__ ssend, float4* __restrict__ swx, float4* __restrict__ swy,
    const int* __restrict__ eid, const float* __restrict__ relpos,
    const float* __restrict__ wsup, const int* __restrict__ senders, int E)
{
    int p = blockIdx.x * 256 + threadIdx.x;
    if (p >= E) return;
    int e = eid[p];
    float ws = wsup[0];
    float2 rp = *(const float2*)(relpos + 2 * e);
    float u0 = fminf(fmaxf(rp.x / ws, -1.f), 1.f);
    float u1 = fminf(fmaxf(rp.y / ws, -1.f), 1.f);
    float gx = (u0 + 1.f) * 1.5f;
    float gy = (u1 + 1.f) * 1.5f;
    float x0f = fminf(fmaxf(floorf(gx), 0.f), 2.f);
    float y0f = fminf(fmaxf(floorf(gy), 0.f), 2.f);
    float fx = gx - x0f, fy = gy - y0f;
    int x0i = (int)x0f, y0i = (int)y0f;
    float r2 = u0 * u0 + u1 * u1;
    float win = fmaxf(1.f - r2, 0.f);
    win = win * win * win;
    float wx[4], wy[4];
    #pragma unroll
    for (int k = 0; k < 4; ++k)
        wx[k] = win * ((k == x0i) ? (1.f - fx) : ((k == x0i + 1) ? fx : 0.f));
    #pragma unroll
    for (int k = 0; k < 4; ++k)
        wy[k] = (k == y0i) ? (1.f - fy) : ((k == y0i + 1) ? fy : 0.f);
    ssend[p] = senders[e];
    swx[p] = make_float4(wx[0], wx[1], wx[2], wx[3]);
    swy[p] = make_float4(wy[0], wy[1], wy[2], wy[3]);
}

// ---------------- Phase 1: per-receiver register accumulation -> bf16 A -----
__global__ __launch_bounds__(256) void ascc_accum(
    u16* __restrict__ Abf,
    const float* __restrict__ features,
    const int* __restrict__ off,
    const int* __restrict__ ssend,
    const float4* __restrict__ swx,
    const float4* __restrict__ swy,
    int Nn)
{
    int lane = threadIdx.x & 63;
    int r = blockIdx.x * 4 + (threadIdx.x >> 6);
    if (r >= Nn) return;

    float acc[T_TAPS];
    #pragma unroll
    for (int t = 0; t < T_TAPS; ++t) acc[t] = 0.f;

    int j0 = off[r], j1 = off[r + 1];
    for (int j = j0; j < j1; ++j) {
        int s = ssend[j];
        float4 wx = swx[j];
        float4 wy = swy[j];
        float g = features[(size_t)s * 64 + lane];
        float wxa[4] = {wx.x, wx.y, wx.z, wx.w};
        float wyg[4] = {wy.x * g, wy.y * g, wy.z * g, wy.w * g};
        #pragma unroll
        for (int t = 0; t < T_TAPS; ++t)
            acc[t] += wxa[t >> 2] * wyg[t & 3];
    }

    u16* base = Abf + (size_t)r * 1024 + lane;
    #pragma unroll
    for (int t = 0; t < T_TAPS; ++t) base[t * 64] = f2bf(acc[t]);
}

// ---------------- kernel tensor: antisymmetrize + transpose -> bf16 --------
// KfT[o][k], k = t*64+i ; t=x*4+y ; y<2: +kern[x][y][i][o] ; else -kern[3-x][3-y][i][o]
__global__ __launch_bounds__(256) void ascc_kft(
    u16* __restrict__ KfT, const float* __restrict__ kern)
{
    int idx = blockIdx.x * 256 + threadIdx.x;   // 64*1024
    int o = idx >> 10;
    int k = idx & 1023;
    int t = k >> 6, i = k & 63;
    int x = t >> 2, y = t & 3;
    float val;
    if (y < 2) val =  kern[(((x * 2 + y) * 64) + i) * 64 + o];
    else       val = -kern[((((3 - x) * 2 + (3 - y)) * 64) + i) * 64 + o];
    KfT[(size_t)o * 1024 + k] = f2bf(val);
}

// ---------------- Phase 2: MFMA GEMM out[N,64] = A[N,1024] * Kf[1024,64] ----
__global__ __launch_bounds__(256) void ascc_mgemm(
    float* __restrict__ out,
    const u16* __restrict__ Abf,
    const u16* __restrict__ KfT,
    const float* __restrict__ bias,
    int Nn)
{
    __shared__ u16 Al[64 * 128];   // [row][k] bf16, XOR-swizzled 16B granules
    __shared__ u16 Bl[64 * 128];   // [o][k]  bf16, XOR-swizzled

    const int tid = threadIdx.x;
    const int lane = tid & 63;
    const int w = tid >> 6;
    const int n0 = blockIdx.x * 64;

    f32x4 acc[4] = {};

    for (int kc = 0; kc < 1024; kc += 128) {
        __syncthreads();
        // stage A tile: 64 rows x 128 k (bf16). 4 threads/row, 64B each.
        {
            int row = tid >> 2, seg = tid & 3;
            int n = n0 + row;
            const u16* src = Abf + (size_t)n * 1024 + kc + seg * 32;
            char* dst = (char*)Al + row * 256;
            u16x8 z = {0, 0, 0, 0, 0, 0, 0, 0};
            #pragma unroll
            for (int g2 = 0; g2 < 4; ++g2) {
                u16x8 v = (n < Nn) ? *(const u16x8*)(src + g2 * 8) : z;
                int colb = seg * 64 + g2 * 16;
                *(u16x8*)(dst + (colb ^ ((row & 7) << 4))) = v;
            }
        }
        // stage B tile: 64 outs x 128 k (bf16)
        {
            int row = tid >> 2, seg = tid & 3;
            const u16* src = KfT + (size_t)row * 1024 + kc + seg * 32;
            char* dst = (char*)Bl + row * 256;
            #pragma unroll
            for (int g2 = 0; g2 < 4; ++g2) {
                u16x8 v = *(const u16x8*)(src + g2 * 8);
                int colb = seg * 64 + g2 * 16;
                *(u16x8*)(dst + (colb ^ ((row & 7) << 4))) = v;
            }
        }
        __syncthreads();
        // compute: each wave: rows w*16..w*16+15, all 64 cols (4 tiles)
        int wr = w << 4;
        #pragma unroll
        for (int ks = 0; ks < 4; ++ks) {
            int arow = wr + (lane & 15);
            int kb = ks * 64 + ((lane >> 4) << 4);
            s16x8 af = *(const s16x8*)((char*)Al + arow * 256 + (kb ^ ((arow & 7) << 4)));
            #pragma unroll
            for (int t = 0; t < 4; ++t) {
                int brow = (t << 4) + (lane & 15);
                s16x8 bf = *(const s16x8*)((char*)Bl + brow * 256 + (kb ^ ((brow & 7) << 4)));
                acc[t] = __builtin_amdgcn_mfma_f32_16x16x32_bf16(af, bf, acc[t], 0, 0, 0);
            }
        }
    }

    // epilogue: D row = (lane>>4)*4 + reg, col = t*16 + (lane&15)
    int rbase = n0 + (w << 4) + ((lane >> 4) << 2);
    #pragma unroll
    for (int t = 0; t < 4; ++t) {
        int col = (t << 4) + (lane & 15);
        float bv = bias[col];
        #pragma unroll
        for (int reg = 0; reg < 4; ++reg) {
            int n = rbase + reg;
            if (n < Nn) out[(size_t)n * 64 + col] = acc[t][reg] + bv;
        }
    }
}

extern "C" void kernel_launch(void* const* d_in, const int* in_sizes, int n_in,
                              void* d_out, int out_size, void* d_ws, size_t ws_size,
                              hipStream_t stream) {
    const float* features  = (const float*)d_in[0];
    const int*   receivers = (const int*)d_in[1];
    const float* relpos    = (const float*)d_in[2];
    const float* wsup      = (const float*)d_in[3];
    const int*   senders   = (const int*)d_in[4];
    const float* kern      = (const float*)d_in[5];
    const float* bias      = (const float*)d_in[6];
    float* out = (float*)d_out;

    const int Nn = in_sizes[0] / 64;
    const int E  = in_sizes[1];

    // ws layout: off[N+1] | cur[N] | eid[E] | ssend[E] | swx[E]f4 | swy[E]f4 | KfT[64*1024]u16 | Abf[N*1024]u16
    char* wp = (char*)d_ws;
    size_t p = 0;
    auto take = [&](size_t bytes) { char* q = wp + p; p = (p + bytes + 255) & ~(size_t)255; return q; };
    int*    off   = (int*)take((size_t)(Nn + 1) * 4);
    int*    cur   = (int*)take((size_t)Nn * 4);
    int*    eid   = (int*)take((size_t)E * 4);
    int*    ssend = (int*)take((size_t)E * 4);
    float4* swx   = (float4*)take((size_t)E * 16);
    float4* swy   = (float4*)take((size_t)E * 16);
    u16*    KfT   = (u16*)take((size_t)64 * 1024 * 2);
    u16*    Abf   = (u16*)take((size_t)Nn * 1024 * 2);
    (void)ws_size;

    dim3 ge((E + 255) / 256), gn((Nn + 255) / 256);

    ascc_kft<<<dim3(256), dim3(256), 0, stream>>>(KfT, kern);

    hipMemsetAsync(cur, 0, (size_t)Nn * sizeof(int), stream);
    ascc_hist<<<ge, dim3(256), 0, stream>>>(cur, receivers, E);
    ascc_scan<<<dim3(1), dim3(1024), 0, stream>>>(off, cur, Nn);
    ascc_copy<<<gn, dim3(256), 0, stream>>>(cur, off, Nn);
    ascc_fill<<<ge, dim3(256), 0, stream>>>(eid, cur, receivers, E);
    ascc_prep<<<ge, dim3(256), 0, stream>>>(ssend, swx, swy, eid, relpos, wsup, senders, E);

    ascc_accum<<<dim3((Nn + 3) / 4), dim3(256), 0, stream>>>(
        Abf, features, off, ssend, swx, swy, Nn);

    ascc_mgemm<<<dim3((Nn + 63) / 64), dim3(256), 0, stream>>>(
        out, Abf, KfT, bias, Nn);
}

// Round 4
// 210.429 us; speedup vs baseline: 3.7377x; 1.3677x over previous
//
#include <hip/hip_runtime.h>
#include <hip/hip_bf16.h>

// Inputs: 0 features[N,64] f32 | 1 receivers[E] i32 | 2 relpos[E,2] f32
//         3 window_support[1] f32 | 4 senders[E] i32 | 5 kernel[4,2,64,64] f32
//         6 bias[64] f32   -> out [N,64] f32

#define T_TAPS 16

typedef unsigned short u16;
typedef short s16x8 __attribute__((ext_vector_type(8)));
typedef u16 u16x8 __attribute__((ext_vector_type(8)));
typedef float f32x4 __attribute__((ext_vector_type(4)));

static __device__ __forceinline__ u16 f2bf(float x) {
    union { float f; unsigned u; } v; v.f = x;
    unsigned r = v.u + 0x7FFF + ((v.u >> 16) & 1);
    return (u16)(r >> 16);
}

// ---------------- CSR build ----------------
__global__ __launch_bounds__(256) void ascc_hist(
    int* __restrict__ cnt, const int* __restrict__ receivers, int E)
{
    int e = blockIdx.x * 256 + threadIdx.x;
    if (e < E) atomicAdd(&cnt[receivers[e]], 1);
}

// hierarchical scan: 2048 elems/block
__global__ __launch_bounds__(256) void ascc_scan1(
    int* __restrict__ bsum, const int* __restrict__ cnt, int Nn)
{
    __shared__ int red[256];
    int i0 = blockIdx.x * 2048 + threadIdx.x * 8;
    int s = 0;
    #pragma unroll
    for (int k = 0; k < 8; ++k) { int i = i0 + k; if (i < Nn) s += cnt[i]; }
    red[threadIdx.x] = s;
    __syncthreads();
    #pragma unroll
    for (int d = 128; d > 0; d >>= 1) {
        if (threadIdx.x < d) red[threadIdx.x] += red[threadIdx.x + d];
        __syncthreads();
    }
    if (threadIdx.x == 0) bsum[blockIdx.x] = red[0];
}

__global__ __launch_bounds__(256) void ascc_scan2(
    int* __restrict__ boff, int* __restrict__ off,
    const int* __restrict__ bsum, int NB, int Nn)
{
    __shared__ int s[256];
    int x = (threadIdx.x < NB) ? bsum[threadIdx.x] : 0;
    s[threadIdx.x] = x;
    __syncthreads();
    #pragma unroll
    for (int d = 1; d < 256; d <<= 1) {
        int t = (threadIdx.x >= d) ? s[threadIdx.x - d] : 0;
        __syncthreads();
        s[threadIdx.x] += t;
        __syncthreads();
    }
    if (threadIdx.x < NB) boff[threadIdx.x] = s[threadIdx.x] - x;
    if (threadIdx.x == 255) off[Nn] = s[255];
}

__global__ __launch_bounds__(256) void ascc_scan3(
    int* __restrict__ off, int* __restrict__ cur,
    const int* __restrict__ cnt, const int* __restrict__ boff, int Nn)
{
    __shared__ int s[256];
    int i0 = blockIdx.x * 2048 + threadIdx.x * 8;
    int x[8]; int ts = 0;
    #pragma unroll
    for (int k = 0; k < 8; ++k) { int i = i0 + k; x[k] = (i < Nn) ? cnt[i] : 0; ts += x[k]; }
    s[threadIdx.x] = ts;
    __syncthreads();
    #pragma unroll
    for (int d = 1; d < 256; d <<= 1) {
        int t = (threadIdx.x >= d) ? s[threadIdx.x - d] : 0;
        __syncthreads();
        s[threadIdx.x] += t;
        __syncthreads();
    }
    int run = boff[blockIdx.x] + s[threadIdx.x] - ts;
    #pragma unroll
    for (int k = 0; k < 8; ++k) {
        int i = i0 + k;
        if (i < Nn) { off[i] = run; cur[i] = run; }
        run += x[k];
    }
}

// ---------- fused fill+prep: claim sorted slot, write edge record -----------
__global__ __launch_bounds__(256) void ascc_fillprep(
    int* __restrict__ ssend, float4* __restrict__ swx, float4* __restrict__ swy,
    int* __restrict__ cur, const int* __restrict__ receivers,
    const float* __restrict__ relpos, const float* __restrict__ wsup,
    const int* __restrict__ senders, int E)
{
    int e = blockIdx.x * 256 + threadIdx.x;
    if (e >= E) return;
    int p = atomicAdd(&cur[receivers[e]], 1);

    float ws = wsup[0];
    float2 rp = *(const float2*)(relpos + 2 * e);
    float u0 = fminf(fmaxf(rp.x / ws, -1.f), 1.f);
    float u1 = fminf(fmaxf(rp.y / ws, -1.f), 1.f);
    float gx = (u0 + 1.f) * 1.5f;
    float gy = (u1 + 1.f) * 1.5f;
    float x0f = fminf(fmaxf(floorf(gx), 0.f), 2.f);
    float y0f = fminf(fmaxf(floorf(gy), 0.f), 2.f);
    float fx = gx - x0f, fy = gy - y0f;
    int x0i = (int)x0f, y0i = (int)y0f;
    float r2 = u0 * u0 + u1 * u1;
    float win = fmaxf(1.f - r2, 0.f);
    win = win * win * win;
    float wx[4], wy[4];
    #pragma unroll
    for (int k = 0; k < 4; ++k)
        wx[k] = win * ((k == x0i) ? (1.f - fx) : ((k == x0i + 1) ? fx : 0.f));
    #pragma unroll
    for (int k = 0; k < 4; ++k)
        wy[k] = (k == y0i) ? (1.f - fy) : ((k == y0i + 1) ? fy : 0.f);

    ssend[p] = senders[e];
    swx[p] = make_float4(wx[0], wx[1], wx[2], wx[3]);
    swy[p] = make_float4(wy[0], wy[1], wy[2], wy[3]);
}

// ---------------- Phase 1: per-receiver register accumulation -> bf16 A -----
// one wave per receiver; lane = channel; 4-edge unroll for memory-level par.
__global__ __launch_bounds__(256) void ascc_accum(
    u16* __restrict__ Abf,
    const float* __restrict__ features,
    const int* __restrict__ off,
    const int* __restrict__ ssend,
    const float4* __restrict__ swx,
    const float4* __restrict__ swy,
    int Nn)
{
    int lane = threadIdx.x & 63;
    int r = blockIdx.x * 4 + (threadIdx.x >> 6);
    if (r >= Nn) return;

    float acc[T_TAPS];
    #pragma unroll
    for (int t = 0; t < T_TAPS; ++t) acc[t] = 0.f;

    int j0 = off[r], j1 = off[r + 1];
    int j = j0;
    for (; j + 4 <= j1; j += 4) {
        int s0 = ssend[j], s1 = ssend[j + 1], s2 = ssend[j + 2], s3 = ssend[j + 3];
        float4 wxv0 = swx[j], wxv1 = swx[j + 1], wxv2 = swx[j + 2], wxv3 = swx[j + 3];
        float4 wyv0 = swy[j], wyv1 = swy[j + 1], wyv2 = swy[j + 2], wyv3 = swy[j + 3];
        float g0 = features[(size_t)s0 * 64 + lane];
        float g1 = features[(size_t)s1 * 64 + lane];
        float g2 = features[(size_t)s2 * 64 + lane];
        float g3 = features[(size_t)s3 * 64 + lane];
        {
            float wxa[4] = {wxv0.x, wxv0.y, wxv0.z, wxv0.w};
            float wyg[4] = {wyv0.x * g0, wyv0.y * g0, wyv0.z * g0, wyv0.w * g0};
            #pragma unroll
            for (int t = 0; t < T_TAPS; ++t) acc[t] += wxa[t >> 2] * wyg[t & 3];
        }
        {
            float wxa[4] = {wxv1.x, wxv1.y, wxv1.z, wxv1.w};
            float wyg[4] = {wyv1.x * g1, wyv1.y * g1, wyv1.z * g1, wyv1.w * g1};
            #pragma unroll
            for (int t = 0; t < T_TAPS; ++t) acc[t] += wxa[t >> 2] * wyg[t & 3];
        }
        {
            float wxa[4] = {wxv2.x, wxv2.y, wxv2.z, wxv2.w};
            float wyg[4] = {wyv2.x * g2, wyv2.y * g2, wyv2.z * g2, wyv2.w * g2};
            #pragma unroll
            for (int t = 0; t < T_TAPS; ++t) acc[t] += wxa[t >> 2] * wyg[t & 3];
        }
        {
            float wxa[4] = {wxv3.x, wxv3.y, wxv3.z, wxv3.w};
            float wyg[4] = {wyv3.x * g3, wyv3.y * g3, wyv3.z * g3, wyv3.w * g3};
            #pragma unroll
            for (int t = 0; t < T_TAPS; ++t) acc[t] += wxa[t >> 2] * wyg[t & 3];
        }
    }
    for (; j < j1; ++j) {
        int s = ssend[j];
        float4 wx = swx[j];
        float4 wy = swy[j];
        float g = features[(size_t)s * 64 + lane];
        float wxa[4] = {wx.x, wx.y, wx.z, wx.w};
        float wyg[4] = {wy.x * g, wy.y * g, wy.z * g, wy.w * g};
        #pragma unroll
        for (int t = 0; t < T_TAPS; ++t) acc[t] += wxa[t >> 2] * wyg[t & 3];
    }

    u16* base = Abf + (size_t)r * 1024 + lane;
    #pragma unroll
    for (int t = 0; t < T_TAPS; ++t) base[t * 64] = f2bf(acc[t]);
}

// ---------------- kernel tensor: antisymmetrize + transpose -> bf16 --------
__global__ __launch_bounds__(256) void ascc_kft(
    u16* __restrict__ KfT, const float* __restrict__ kern)
{
    int idx = blockIdx.x * 256 + threadIdx.x;   // 64*1024
    int o = idx >> 10;
    int k = idx & 1023;
    int t = k >> 6, i = k & 63;
    int x = t >> 2, y = t & 3;
    float val;
    if (y < 2) val =  kern[(((x * 2 + y) * 64) + i) * 64 + o];
    else       val = -kern[((((3 - x) * 2 + (3 - y)) * 64) + i) * 64 + o];
    KfT[(size_t)o * 1024 + k] = f2bf(val);
}

// ---------------- Phase 2: MFMA GEMM out[N,64] = A[N,1024] * Kf[1024,64] ----
__global__ __launch_bounds__(256) void ascc_mgemm(
    float* __restrict__ out,
    const u16* __restrict__ Abf,
    const u16* __restrict__ KfT,
    const float* __restrict__ bias,
    int Nn)
{
    __shared__ u16 Al[64 * 128];
    __shared__ u16 Bl[64 * 128];

    const int tid = threadIdx.x;
    const int lane = tid & 63;
    const int w = tid >> 6;
    const int n0 = blockIdx.x * 64;

    f32x4 acc[4] = {};

    for (int kc = 0; kc < 1024; kc += 128) {
        __syncthreads();
        {
            int row = tid >> 2, seg = tid & 3;
            int n = n0 + row;
            const u16* src = Abf + (size_t)n * 1024 + kc + seg * 32;
            char* dst = (char*)Al + row * 256;
            u16x8 z = {0, 0, 0, 0, 0, 0, 0, 0};
            #pragma unroll
            for (int g2 = 0; g2 < 4; ++g2) {
                u16x8 v = (n < Nn) ? *(const u16x8*)(src + g2 * 8) : z;
                int colb = seg * 64 + g2 * 16;
                *(u16x8*)(dst + (colb ^ ((row & 7) << 4))) = v;
            }
        }
        {
            int row = tid >> 2, seg = tid & 3;
            const u16* src = KfT + (size_t)row * 1024 + kc + seg * 32;
            char* dst = (char*)Bl + row * 256;
            #pragma unroll
            for (int g2 = 0; g2 < 4; ++g2) {
                u16x8 v = *(const u16x8*)(src + g2 * 8);
                int colb = seg * 64 + g2 * 16;
                *(u16x8*)(dst + (colb ^ ((row & 7) << 4))) = v;
            }
        }
        __syncthreads();
        int wr = w << 4;
        #pragma unroll
        for (int ks = 0; ks < 4; ++ks) {
            int arow = wr + (lane & 15);
            int kb = ks * 64 + ((lane >> 4) << 4);
            s16x8 af = *(const s16x8*)((char*)Al + arow * 256 + (kb ^ ((arow & 7) << 4)));
            #pragma unroll
            for (int t = 0; t < 4; ++t) {
                int brow = (t << 4) + (lane & 15);
                s16x8 bf = *(const s16x8*)((char*)Bl + brow * 256 + (kb ^ ((brow & 7) << 4)));
                acc[t] = __builtin_amdgcn_mfma_f32_16x16x32_bf16(af, bf, acc[t], 0, 0, 0);
            }
        }
    }

    int rbase = n0 + (w << 4) + ((lane >> 4) << 2);
    #pragma unroll
    for (int t = 0; t < 4; ++t) {
        int col = (t << 4) + (lane & 15);
        float bv = bias[col];
        #pragma unroll
        for (int reg = 0; reg < 4; ++reg) {
            int n = rbase + reg;
            if (n < Nn) out[(size_t)n * 64 + col] = acc[t][reg] + bv;
        }
    }
}

extern "C" void kernel_launch(void* const* d_in, const int* in_sizes, int n_in,
                              void* d_out, int out_size, void* d_ws, size_t ws_size,
                              hipStream_t stream) {
    const float* features  = (const float*)d_in[0];
    const int*   receivers = (const int*)d_in[1];
    const float* relpos    = (const float*)d_in[2];
    const float* wsup      = (const float*)d_in[3];
    const int*   senders   = (const int*)d_in[4];
    const float* kern      = (const float*)d_in[5];
    const float* bias      = (const float*)d_in[6];
    float* out = (float*)d_out;

    const int Nn = in_sizes[0] / 64;
    const int E  = in_sizes[1];
    const int NB = (Nn + 2047) / 2048;   // scan blocks (<=256)

    // ws: off[N+1] | cur[N] | bsum[NB] | boff[NB] | ssend[E] | swx[E] | swy[E] | KfT | Abf
    char* wp = (char*)d_ws;
    size_t p = 0;
    auto take = [&](size_t bytes) { char* q = wp + p; p = (p + bytes + 255) & ~(size_t)255; return q; };
    int*    off   = (int*)take((size_t)(Nn + 1) * 4);
    int*    cur   = (int*)take((size_t)Nn * 4);
    int*    bsum  = (int*)take((size_t)NB * 4);
    int*    boff  = (int*)take((size_t)NB * 4);
    int*    ssend = (int*)take((size_t)E * 4);
    float4* swx   = (float4*)take((size_t)E * 16);
    float4* swy   = (float4*)take((size_t)E * 16);
    u16*    KfT   = (u16*)take((size_t)64 * 1024 * 2);
    u16*    Abf   = (u16*)take((size_t)Nn * 1024 * 2);
    (void)ws_size;

    dim3 ge((E + 255) / 256);

    ascc_kft<<<dim3(256), dim3(256), 0, stream>>>(KfT, kern);

    hipMemsetAsync(cur, 0, (size_t)Nn * sizeof(int), stream);
    ascc_hist<<<ge, dim3(256), 0, stream>>>(cur, receivers, E);
    ascc_scan1<<<dim3(NB), dim3(256), 0, stream>>>(bsum, cur, Nn);
    ascc_scan2<<<dim3(1), dim3(256), 0, stream>>>(boff, off, bsum, NB, Nn);
    ascc_scan3<<<dim3(NB), dim3(256), 0, stream>>>(off, cur, cur, boff, Nn);
    ascc_fillprep<<<ge, dim3(256), 0, stream>>>(
        ssend, swx, swy, cur, receivers, relpos, wsup, senders, E);

    ascc_accum<<<dim3((Nn + 3) / 4), dim3(256), 0, stream>>>(
        Abf, features, off, ssend, swx, swy, Nn);

    ascc_mgemm<<<dim3((Nn + 63) / 64), dim3(256), 0, stream>>>(
        out, Abf, KfT, bias, Nn);
}